// Round 7
// baseline (337.257 us; speedup 1.0000x reference)
//
#include <hip/hip_runtime.h>

#define CC 128
#define SS 4096
#define L2E 1.44269504f

typedef _Float16 f16;
typedef f16 f16x8 __attribute__((ext_vector_type(8)));
typedef float f32x4 __attribute__((ext_vector_type(4)));

struct PArg { const float *x, *w, *b, *sc, *bb, *bm, *bv; f16* out; };

// ---------------------------------------------------------------- proj (MFMA, prep fused)
// grid (256, 3): y=p, x = b*64 + st. p=0,1 -> [B][S][C]; p=2 -> [B][C][S].
__global__ __launch_bounds__(256) void projk(PArg A0, PArg A1, PArg A2, int* __restrict__ cnt) {
    const int p = blockIdx.y;
    PArg A = (p == 0) ? A0 : ((p == 1) ? A1 : A2);
    const int bx = blockIdx.x;
    const int b  = bx >> 6;
    const int s0 = (bx & 63) * 64;
    const int tid = threadIdx.x;
    const int w = tid >> 6, lane = tid & 63;
    const int n = lane & 15, g = lane >> 4;

    __shared__ f16 Xl[64][136];                 // X^T tile [s][c]
    __shared__ f16 Wl[128][136];                // Weff [o][c], aliased as Yl
    __shared__ float invA[128], ebA[128];
    f16* Yl = &Wl[0][0];

    if (p == 0 && bx == 0 && tid < 128) cnt[tid] = 0;   // zero merge counters (stream-ordered)
    if (tid < 128) {
        float iv = A.sc[tid] * rsqrtf(A.bv[tid] + 1e-5f);
        invA[tid] = iv;
        ebA[tid] = (A.b[tid] - A.bm[tid]) * iv + A.bb[tid];
    }
    // stage X: fp32 [c][s] -> f16 [s][c]
#pragma unroll
    for (int i = 0; i < 8; ++i) {
        int vi = tid + i * 256;                 // 0..2047
        int c = vi >> 4, sq = (vi & 15) * 4;
        float4 v = *(const float4*)(A.x + ((size_t)b * CC + c) * SS + s0 + sq);
        Xl[sq + 0][c] = (f16)v.x; Xl[sq + 1][c] = (f16)v.y;
        Xl[sq + 2][c] = (f16)v.z; Xl[sq + 3][c] = (f16)v.w;
    }
    __syncthreads();                            // invA ready
    // stage W (fp32 -> f16, folded inv)
#pragma unroll
    for (int i = 0; i < 8; ++i) {
        int vi = tid + i * 256;
        int o = vi >> 4, cq = (vi & 15) * 8;
        const float* wp = A.w + o * CC + cq;
        float4 a = *(const float4*)wp;
        float4 b4 = *(const float4*)(wp + 4);
        float iv = invA[o];
        union { f16 h[8]; uint4 u; } pk;
        pk.h[0] = (f16)(a.x * iv);  pk.h[1] = (f16)(a.y * iv);
        pk.h[2] = (f16)(a.z * iv);  pk.h[3] = (f16)(a.w * iv);
        pk.h[4] = (f16)(b4.x * iv); pk.h[5] = (f16)(b4.y * iv);
        pk.h[6] = (f16)(b4.z * iv); pk.h[7] = (f16)(b4.w * iv);
        *(uint4*)&Wl[o][cq] = pk.u;
    }
    __syncthreads();

    if (p < 2) {
        // D[m=o][n=s]: A=Weff, B=X. Wave w: o in [w*32, w*32+32), all 64 s.
        f32x4 acc[2][4];
#pragma unroll
        for (int mt = 0; mt < 2; ++mt)
#pragma unroll
            for (int nt = 0; nt < 4; ++nt) acc[mt][nt] = (f32x4){0.f, 0.f, 0.f, 0.f};
#pragma unroll
        for (int ks = 0; ks < 4; ++ks) {
            f16x8 af[2], bf[4];
#pragma unroll
            for (int mt = 0; mt < 2; ++mt) af[mt] = *(const f16x8*)&Wl[w * 32 + mt * 16 + n][ks * 32 + g * 8];
#pragma unroll
            for (int nt = 0; nt < 4; ++nt) bf[nt] = *(const f16x8*)&Xl[nt * 16 + n][ks * 32 + g * 8];
#pragma unroll
            for (int mt = 0; mt < 2; ++mt)
#pragma unroll
                for (int nt = 0; nt < 4; ++nt)
                    acc[mt][nt] = __builtin_amdgcn_mfma_f32_16x16x32_f16(af[mt], bf[nt], acc[mt][nt], 0, 0, 0);
        }
        __syncthreads();
#pragma unroll
        for (int mt = 0; mt < 2; ++mt) {
            float ebr[4];
#pragma unroll
            for (int r = 0; r < 4; ++r) ebr[r] = ebA[w * 32 + mt * 16 + g * 4 + r];
#pragma unroll
            for (int nt = 0; nt < 4; ++nt) {
                union { f16 h[4]; uint2 u; } pk;
#pragma unroll
                for (int r = 0; r < 4; ++r) {
                    float y = acc[mt][nt][r] + ebr[r];
                    y = (y > 0.f) ? y : (expf(y) - 1.f);
                    pk.h[r] = (f16)y;
                }
                *(uint2*)&Yl[(nt * 16 + n) * 136 + w * 32 + mt * 16 + g * 4] = pk.u;
            }
        }
        __syncthreads();
#pragma unroll
        for (int i = 0; i < 4; ++i) {
            int vi = tid + i * 256;
            int s = vi >> 4, cl = (vi & 15) * 8;
            *(uint4*)&A.out[((size_t)b * SS + s0 + s) * CC + cl] = *(const uint4*)&Yl[s * 136 + cl];
        }
    } else {
        // D[m=s][n=o]: A=X, B=Weff. Wave w: s in [w*16, w*16+16), all 128 o.
        f32x4 acc[8];
#pragma unroll
        for (int nt = 0; nt < 8; ++nt) acc[nt] = (f32x4){0.f, 0.f, 0.f, 0.f};
#pragma unroll
        for (int ks = 0; ks < 4; ++ks) {
            f16x8 af = *(const f16x8*)&Xl[w * 16 + n][ks * 32 + g * 8];
#pragma unroll
            for (int nt = 0; nt < 8; ++nt) {
                f16x8 bf = *(const f16x8*)&Wl[nt * 16 + n][ks * 32 + g * 8];
                acc[nt] = __builtin_amdgcn_mfma_f32_16x16x32_f16(af, bf, acc[nt], 0, 0, 0);
            }
        }
        __syncthreads();
#pragma unroll
        for (int nt = 0; nt < 8; ++nt) {
            float ebc = ebA[nt * 16 + n];
            union { f16 h[4]; uint2 u; } pk;
#pragma unroll
            for (int r = 0; r < 4; ++r) {
                float y = acc[nt][r] + ebc;
                y = (y > 0.f) ? y : (expf(y) - 1.f);
                pk.h[r] = (f16)y;
            }
            *(uint2*)&Yl[(nt * 16 + n) * 136 + w * 16 + g * 4] = pk.u;   // Yl[o][s]
        }
        __syncthreads();
#pragma unroll
        for (int i = 0; i < 4; ++i) {
            int vi = tid + i * 256;
            int o = vi >> 3, sl = (vi & 7) * 8;
            *(uint4*)&A.out[((size_t)b * CC + o) * SS + s0 + sl] = *(const uint4*)&Yl[o * 136 + sl];
        }
    }
}

// ---------------------------------------------------------------- attention + fused merge
// grid 512 = b(4) x kh(4) x qt(32). 256 threads (4 waves), wave owns 32 q of a 128-q tile.
// 1024 keys per block, 16 steps of 64, register-prefetched staging.
// Last block of each (b,qt) group merges the 4 partials and writes the final output.
__global__ __launch_bounds__(256, 2) void attnk(
    const f16* __restrict__ Qt, const f16* __restrict__ Kt, const f16* __restrict__ Vt,
    f16* __restrict__ Op, float* __restrict__ Ml, int* __restrict__ cnt,
    const float* __restrict__ xv, const float* __restrict__ gp, const float* __restrict__ bp,
    float* __restrict__ out)
{
    const int tid = threadIdx.x;
    const int bx = blockIdx.x;
    const int b  = bx >> 7;
    const int kh = (bx >> 5) & 3;
    const int qt = bx & 31;
    const int q0 = qt * 128;
    const int kbeg = kh * 1024;

    __shared__ f16 Kl[64][136];                 // K tile [key][c]
    __shared__ f16 Vl[128][72];                 // V tile [c][key]
    __shared__ f16 Pl[4][32][72];               // per-wave P [q_local][key]
    __shared__ int lastFlag;

    const int w = tid >> 6, lane = tid & 63;
    const int n = lane & 15, g = lane >> 4;

    // Q fragments straight from global: A[m=q][k=c]
    f16x8 qf[2][4];
    {
        const f16* Qb = Qt + ((size_t)b * SS + q0 + w * 32) * CC;
#pragma unroll
        for (int mt = 0; mt < 2; ++mt)
#pragma unroll
            for (int ks = 0; ks < 4; ++ks)
                qf[mt][ks] = *(const f16x8*)&Qb[(mt * 16 + n) * CC + ks * 32 + g * 8];
    }

    f32x4 oacc[2][8];
#pragma unroll
    for (int mt = 0; mt < 2; ++mt)
#pragma unroll
        for (int nt = 0; nt < 8; ++nt) oacc[mt][nt] = (f32x4){0.f, 0.f, 0.f, 0.f};
    float mreg[2][4], lsum[2][4];
#pragma unroll
    for (int mt = 0; mt < 2; ++mt)
#pragma unroll
        for (int r = 0; r < 4; ++r) { mreg[mt][r] = -1e30f; lsum[mt][r] = 0.f; }

    // register prefetch of tile 0
    uint4 pk4[4], pv4[4];
#pragma unroll
    for (int i = 0; i < 4; ++i) {
        int vi = tid + i * 256;
        int rk = vi >> 4, ck = (vi & 15) * 8;
        pk4[i] = *(const uint4*)&Kt[((size_t)b * SS + kbeg + rk) * CC + ck];
        int rv = vi >> 3, cv = (vi & 7) * 8;
        pv4[i] = *(const uint4*)&Vt[((size_t)b * CC + rv) * SS + kbeg + cv];
    }

    for (int kt = 0; kt < 16; ++kt) {
        const int k0 = kbeg + kt * 64;
        __syncthreads();                        // prev-step LDS reads done
        // write prefetched tile to LDS
#pragma unroll
        for (int i = 0; i < 4; ++i) {
            int vi = tid + i * 256;
            int rk = vi >> 4, ck = (vi & 15) * 8;
            *(uint4*)&Kl[rk][ck] = pk4[i];
            int rv = vi >> 3, cv = (vi & 7) * 8;
            *(uint4*)&Vl[rv][cv] = pv4[i];
        }
        // prefetch next tile (overlaps with compute below)
        if (kt < 15) {
#pragma unroll
            for (int i = 0; i < 4; ++i) {
                int vi = tid + i * 256;
                int rk = vi >> 4, ck = (vi & 15) * 8;
                pk4[i] = *(const uint4*)&Kt[((size_t)b * SS + k0 + 64 + rk) * CC + ck];
                int rv = vi >> 3, cv = (vi & 7) * 8;
                pv4[i] = *(const uint4*)&Vt[((size_t)b * CC + rv) * SS + k0 + 64 + cv];
            }
        }
        __syncthreads();                        // tiles ready

        // phase A: S[q][key] = Q.K^T
        f32x4 sacc[2][4];
#pragma unroll
        for (int mt = 0; mt < 2; ++mt)
#pragma unroll
            for (int nt = 0; nt < 4; ++nt) sacc[mt][nt] = (f32x4){0.f, 0.f, 0.f, 0.f};
#pragma unroll
        for (int ks = 0; ks < 4; ++ks) {
            f16x8 kf[4];
#pragma unroll
            for (int nt = 0; nt < 4; ++nt) kf[nt] = *(const f16x8*)&Kl[nt * 16 + n][ks * 32 + g * 8];
#pragma unroll
            for (int mt = 0; mt < 2; ++mt)
#pragma unroll
                for (int nt = 0; nt < 4; ++nt)
                    sacc[mt][nt] = __builtin_amdgcn_mfma_f32_16x16x32_f16(qf[mt][ks], kf[nt], sacc[mt][nt], 0, 0, 0);
        }

        // in-register online softmax; rows q_local = w*32 + mt*16 + g*4 + r
        float al[2][4];
#pragma unroll
        for (int mt = 0; mt < 2; ++mt) {
#pragma unroll
            for (int r = 0; r < 4; ++r) {
                float v = fmaxf(fmaxf(sacc[mt][0][r], sacc[mt][1][r]),
                                fmaxf(sacc[mt][2][r], sacc[mt][3][r]));
                v = fmaxf(v, __shfl_xor(v, 1));
                v = fmaxf(v, __shfl_xor(v, 2));
                v = fmaxf(v, __shfl_xor(v, 4));
                v = fmaxf(v, __shfl_xor(v, 8));
                float mn = fmaxf(mreg[mt][r], v);
                al[mt][r] = exp2f((mreg[mt][r] - mn) * L2E);
                mreg[mt][r] = mn;
                float p[4], rs = 0.f;
#pragma unroll
                for (int nt = 0; nt < 4; ++nt) {
                    p[nt] = exp2f((sacc[mt][nt][r] - mn) * L2E);
                    rs += p[nt];
                    Pl[w][mt * 16 + g * 4 + r][nt * 16 + n] = (f16)p[nt];
                }
                lsum[mt][r] = lsum[mt][r] * al[mt][r] + rs;   // per-lane partial; reduced at end
            }
        }
#pragma unroll
        for (int mt = 0; mt < 2; ++mt)
#pragma unroll
            for (int nt = 0; nt < 8; ++nt)
#pragma unroll
                for (int r = 0; r < 4; ++r) oacc[mt][nt][r] *= al[mt][r];

        // phase B: O[q][c] += P.V^T (Pl wave-private: no barrier needed)
#pragma unroll
        for (int ks = 0; ks < 2; ++ks) {
            f16x8 af2[2], vf[8];
#pragma unroll
            for (int mt = 0; mt < 2; ++mt) af2[mt] = *(const f16x8*)&Pl[w][mt * 16 + n][ks * 32 + g * 8];
#pragma unroll
            for (int nt = 0; nt < 8; ++nt) vf[nt] = *(const f16x8*)&Vl[nt * 16 + n][ks * 32 + g * 8];
#pragma unroll
            for (int mt = 0; mt < 2; ++mt)
#pragma unroll
                for (int nt = 0; nt < 8; ++nt)
                    oacc[mt][nt] = __builtin_amdgcn_mfma_f32_16x16x32_f16(af2[mt], vf[nt], oacc[mt][nt], 0, 0, 0);
        }
    }

    // final l reduction (deferred across all steps)
    float lreg[2][4];
#pragma unroll
    for (int mt = 0; mt < 2; ++mt)
#pragma unroll
        for (int r = 0; r < 4; ++r) {
            float s = lsum[mt][r];
            s += __shfl_xor(s, 1);
            s += __shfl_xor(s, 2);
            s += __shfl_xor(s, 4);
            s += __shfl_xor(s, 8);
            lreg[mt][r] = s;
        }

    // epilogue: partial O^T [c][q] (f16) + m,l per (b,qt,kh)
    const int bqt = b * 32 + qt;
    f16* OpW = Op + ((size_t)bqt * 4 + kh) * 16384;
#pragma unroll
    for (int mt = 0; mt < 2; ++mt)
#pragma unroll
        for (int nt = 0; nt < 8; ++nt) {
            int c = nt * 16 + n;
            int qb = w * 32 + mt * 16 + g * 4;
            union { f16 h[4]; uint2 u; } pk;
#pragma unroll
            for (int r = 0; r < 4; ++r) pk.h[r] = (f16)oacc[mt][nt][r];
            *(uint2*)&OpW[c * 128 + qb] = pk.u;
        }
    if (n == 0) {
        float* MlW = Ml + ((size_t)bqt * 4 + kh) * 256;
#pragma unroll
        for (int mt = 0; mt < 2; ++mt)
#pragma unroll
            for (int r = 0; r < 4; ++r) {
                int q = w * 32 + mt * 16 + g * 4 + r;
                MlW[q]       = mreg[mt][r];
                MlW[128 + q] = lreg[mt][r];
            }
    }

    // ---- last-block merge ----
    __threadfence();                            // release partials (device scope)
    __syncthreads();
    if (tid == 0) lastFlag = (atomicAdd(&cnt[bqt], 1) == 3);
    __syncthreads();
    if (lastFlag) {
        __threadfence();                        // acquire
        const float* ml = Ml + (size_t)bqt * 1024;
        const int q = tid & 127, ch = tid >> 7;
        float m = -1e30f;
#pragma unroll
        for (int k2 = 0; k2 < 4; ++k2) m = fmaxf(m, ml[k2 * 256 + q]);
        float wt[4], tot = 0.f;
#pragma unroll
        for (int k2 = 0; k2 < 4; ++k2) {
            wt[k2] = exp2f((ml[k2 * 256 + q] - m) * L2E);
            tot += wt[k2] * ml[k2 * 256 + 128 + q];
        }
        float inv = 1.f / tot;
        float gm = gp[0], bb = bp[0];
        const f16* O = Op + (size_t)bqt * 4 * 16384;
#pragma unroll 4
        for (int i = 0; i < 64; ++i) {
            int c = ch * 64 + i;
            float o = 0.f;
#pragma unroll
            for (int k2 = 0; k2 < 4; ++k2) o += wt[k2] * (float)O[k2 * 16384 + c * 128 + q];
            o *= inv;
            size_t idx = ((size_t)(b * CC + c)) * SS + q0 + q;
            out[idx] = gm * o + bb * xv[idx];
        }
    }
}

// ---------------------------------------------------------------- launcher
extern "C" void kernel_launch(void* const* d_in, const int* in_sizes, int n_in,
                              void* d_out, int out_size, void* d_ws, size_t ws_size,
                              hipStream_t stream) {
    (void)in_sizes; (void)n_in; (void)out_size; (void)ws_size;

    const size_t TEN = (size_t)4 * SS * CC;          // 2,097,152
    f16* Qt = (f16*)d_ws;                            // 4 MB
    f16* Kt = Qt + TEN;                              // 4 MB
    f16* Vt = Kt + TEN;                              // 4 MB (channel-major)
    f16* Op = Vt + TEN;                              // 512*16384 f16 = 16 MB
    float* Ml = (float*)(Op + (size_t)512 * 16384);  // 512 KB
    int* cnt = (int*)(Ml + 131072);                  // 128 ints

    PArg aq = { (const float*)d_in[0], (const float*)d_in[3],  (const float*)d_in[4],
                (const float*)d_in[5], (const float*)d_in[6],  (const float*)d_in[7],
                (const float*)d_in[8],  Qt };
    PArg ak = { (const float*)d_in[1], (const float*)d_in[9],  (const float*)d_in[10],
                (const float*)d_in[11], (const float*)d_in[12], (const float*)d_in[13],
                (const float*)d_in[14], Kt };
    PArg av = { (const float*)d_in[2], (const float*)d_in[15], (const float*)d_in[16],
                (const float*)d_in[17], (const float*)d_in[18], (const float*)d_in[19],
                (const float*)d_in[20], Vt };

    hipLaunchKernelGGL(projk, dim3(256, 3), dim3(256), 0, stream, aq, ak, av, cnt);
    hipLaunchKernelGGL(attnk, dim3(512), dim3(256), 0, stream, Qt, Kt, Vt, Op, Ml, cnt,
                       (const float*)d_in[2], (const float*)d_in[21], (const float*)d_in[22],
                       (float*)d_out);
}

// Round 8
// 215.944 us; speedup vs baseline: 1.5618x; 1.5618x over previous
//
#include <hip/hip_runtime.h>

#define CC 128
#define SS 4096
#define L2E 1.44269504f

typedef _Float16 f16;
typedef f16 f16x8 __attribute__((ext_vector_type(8)));
typedef float f32x4 __attribute__((ext_vector_type(4)));

struct PArg { const float *x, *w, *b, *sc, *bb, *bm, *bv; f16* out; };

// ---------------------------------------------------------------- proj (MFMA, prep fused)
// grid (256, 3): y=p, x = b*64 + st. p=0,1 -> [B][S][C]; p=2 -> [B][C][S].
__global__ __launch_bounds__(256) void projk(PArg A0, PArg A1, PArg A2) {
    const int p = blockIdx.y;
    PArg A = (p == 0) ? A0 : ((p == 1) ? A1 : A2);
    const int bx = blockIdx.x;
    const int b  = bx >> 6;
    const int s0 = (bx & 63) * 64;
    const int tid = threadIdx.x;
    const int w = tid >> 6, lane = tid & 63;
    const int n = lane & 15, g = lane >> 4;

    __shared__ f16 Xl[64][136];                 // X^T tile [s][c]
    __shared__ f16 Wl[128][136];                // Weff [o][c], aliased as Yl
    __shared__ float invA[128], ebA[128];
    f16* Yl = &Wl[0][0];

    if (tid < 128) {
        float iv = A.sc[tid] * rsqrtf(A.bv[tid] + 1e-5f);
        invA[tid] = iv;
        ebA[tid] = (A.b[tid] - A.bm[tid]) * iv + A.bb[tid];
    }
    // stage X: fp32 [c][s] -> f16 [s][c]
#pragma unroll
    for (int i = 0; i < 8; ++i) {
        int vi = tid + i * 256;                 // 0..2047
        int c = vi >> 4, sq = (vi & 15) * 4;
        float4 v = *(const float4*)(A.x + ((size_t)b * CC + c) * SS + s0 + sq);
        Xl[sq + 0][c] = (f16)v.x; Xl[sq + 1][c] = (f16)v.y;
        Xl[sq + 2][c] = (f16)v.z; Xl[sq + 3][c] = (f16)v.w;
    }
    __syncthreads();                            // invA ready
    // stage W (fp32 -> f16, folded inv)
#pragma unroll
    for (int i = 0; i < 8; ++i) {
        int vi = tid + i * 256;
        int o = vi >> 4, cq = (vi & 15) * 8;
        const float* wp = A.w + o * CC + cq;
        float4 a = *(const float4*)wp;
        float4 b4 = *(const float4*)(wp + 4);
        float iv = invA[o];
        union { f16 h[8]; uint4 u; } pk;
        pk.h[0] = (f16)(a.x * iv);  pk.h[1] = (f16)(a.y * iv);
        pk.h[2] = (f16)(a.z * iv);  pk.h[3] = (f16)(a.w * iv);
        pk.h[4] = (f16)(b4.x * iv); pk.h[5] = (f16)(b4.y * iv);
        pk.h[6] = (f16)(b4.z * iv); pk.h[7] = (f16)(b4.w * iv);
        *(uint4*)&Wl[o][cq] = pk.u;
    }
    __syncthreads();

    if (p < 2) {
        // D[m=o][n=s]: A=Weff, B=X. Wave w: o in [w*32, w*32+32), all 64 s.
        f32x4 acc[2][4];
#pragma unroll
        for (int mt = 0; mt < 2; ++mt)
#pragma unroll
            for (int nt = 0; nt < 4; ++nt) acc[mt][nt] = (f32x4){0.f, 0.f, 0.f, 0.f};
#pragma unroll
        for (int ks = 0; ks < 4; ++ks) {
            f16x8 af[2], bf[4];
#pragma unroll
            for (int mt = 0; mt < 2; ++mt) af[mt] = *(const f16x8*)&Wl[w * 32 + mt * 16 + n][ks * 32 + g * 8];
#pragma unroll
            for (int nt = 0; nt < 4; ++nt) bf[nt] = *(const f16x8*)&Xl[nt * 16 + n][ks * 32 + g * 8];
#pragma unroll
            for (int mt = 0; mt < 2; ++mt)
#pragma unroll
                for (int nt = 0; nt < 4; ++nt)
                    acc[mt][nt] = __builtin_amdgcn_mfma_f32_16x16x32_f16(af[mt], bf[nt], acc[mt][nt], 0, 0, 0);
        }
        __syncthreads();
#pragma unroll
        for (int mt = 0; mt < 2; ++mt) {
            float ebr[4];
#pragma unroll
            for (int r = 0; r < 4; ++r) ebr[r] = ebA[w * 32 + mt * 16 + g * 4 + r];
#pragma unroll
            for (int nt = 0; nt < 4; ++nt) {
                union { f16 h[4]; uint2 u; } pk;
#pragma unroll
                for (int r = 0; r < 4; ++r) {
                    float y = acc[mt][nt][r] + ebr[r];
                    y = (y > 0.f) ? y : (expf(y) - 1.f);
                    pk.h[r] = (f16)y;
                }
                *(uint2*)&Yl[(nt * 16 + n) * 136 + w * 32 + mt * 16 + g * 4] = pk.u;
            }
        }
        __syncthreads();
#pragma unroll
        for (int i = 0; i < 4; ++i) {
            int vi = tid + i * 256;
            int s = vi >> 4, cl = (vi & 15) * 8;
            *(uint4*)&A.out[((size_t)b * SS + s0 + s) * CC + cl] = *(const uint4*)&Yl[s * 136 + cl];
        }
    } else {
        // D[m=s][n=o]: A=X, B=Weff. Wave w: s in [w*16, w*16+16), all 128 o.
        f32x4 acc[8];
#pragma unroll
        for (int nt = 0; nt < 8; ++nt) acc[nt] = (f32x4){0.f, 0.f, 0.f, 0.f};
#pragma unroll
        for (int ks = 0; ks < 4; ++ks) {
            f16x8 af = *(const f16x8*)&Xl[w * 16 + n][ks * 32 + g * 8];
#pragma unroll
            for (int nt = 0; nt < 8; ++nt) {
                f16x8 bf = *(const f16x8*)&Wl[nt * 16 + n][ks * 32 + g * 8];
                acc[nt] = __builtin_amdgcn_mfma_f32_16x16x32_f16(af, bf, acc[nt], 0, 0, 0);
            }
        }
        __syncthreads();
#pragma unroll
        for (int nt = 0; nt < 8; ++nt) {
            float ebc = ebA[nt * 16 + n];
            union { f16 h[4]; uint2 u; } pk;
#pragma unroll
            for (int r = 0; r < 4; ++r) {
                float y = acc[nt][r] + ebc;
                y = (y > 0.f) ? y : (expf(y) - 1.f);
                pk.h[r] = (f16)y;
            }
            *(uint2*)&Yl[(nt * 16 + n) * 136 + w * 16 + g * 4] = pk.u;   // Yl[o][s]
        }
        __syncthreads();
#pragma unroll
        for (int i = 0; i < 4; ++i) {
            int vi = tid + i * 256;
            int o = vi >> 3, sl = (vi & 7) * 8;
            *(uint4*)&A.out[((size_t)b * CC + o) * SS + s0 + sl] = *(const uint4*)&Yl[o * 136 + sl];
        }
    }
}

// ---------------------------------------------------------------- attention
// grid 1024 = b(4) x kh(8) x qt(32), qt fastest. 256 threads (4 waves), wave owns
// 32 q of a 128-q tile. 512 keys/block, 8 steps of 64. S^T orientation:
// phase A computes S^T[key][q] so softmax is 15 in-thread fmax + 2 shuffles per column.
__global__ __launch_bounds__(256, 3) void attnk(
    const f16* __restrict__ Qt, const f16* __restrict__ Kt, const f16* __restrict__ Vt,
    f16* __restrict__ Op, float* __restrict__ Ml)
{
    const int tid = threadIdx.x;
    const int bx = blockIdx.x;
    const int qt = bx & 31;
    const int kh = (bx >> 5) & 7;
    const int b  = bx >> 8;
    const int q0 = qt * 128;
    const int kbeg = kh * 512;

    __shared__ __align__(16) char arena[54272];
    f16 (*Kl)[136] = (f16(*)[136])arena;                 // K tile [key][c]   17408 B
    f16 (*Vl)[72]  = (f16(*)[72])(arena + 17408);        // V tile [c][key]   18432 B

    const int w = tid >> 6, lane = tid & 63;
    const int n = lane & 15, g = lane >> 4;
    f16 (*Pw)[72] = (f16(*)[72])(arena + 35840 + w * 4608);  // wave-private P [q][key]

    // Q B-frags from global: B[k=c][n=q]
    f16x8 qf[2][4];
    {
        const f16* Qb = Qt + ((size_t)b * SS + q0 + w * 32) * CC;
#pragma unroll
        for (int qt2 = 0; qt2 < 2; ++qt2)
#pragma unroll
            for (int ks = 0; ks < 4; ++ks)
                qf[qt2][ks] = *(const f16x8*)&Qb[(qt2 * 16 + n) * CC + ks * 32 + g * 8];
    }

    f32x4 oacc[8][2];
#pragma unroll
    for (int mtc = 0; mtc < 8; ++mtc)
#pragma unroll
        for (int qt2 = 0; qt2 < 2; ++qt2) oacc[mtc][qt2] = (f32x4){0.f, 0.f, 0.f, 0.f};
    float mreg[2] = {-1e30f, -1e30f}, lsum[2] = {0.f, 0.f};

    for (int kt = 0; kt < 8; ++kt) {
        const int k0 = kbeg + kt * 64;
        __syncthreads();                        // prev-step LDS reads done
#pragma unroll
        for (int i = 0; i < 4; ++i) {
            int vi = tid + i * 256;             // 0..1023
            int rk = vi >> 4, ck = (vi & 15) * 8;
            *(uint4*)&Kl[rk][ck] = *(const uint4*)&Kt[((size_t)b * SS + k0 + rk) * CC + ck];
            int rv = vi >> 3, cv = (vi & 7) * 8;
            *(uint4*)&Vl[rv][cv] = *(const uint4*)&Vt[((size_t)b * CC + rv) * SS + k0 + cv];
        }
        __syncthreads();                        // tiles ready

        // phase A: S^T[key][q] = K.Q^T  (A=K, B=Q). key = kt2*16+g*4+r, q = w*32+qt2*16+n
        f32x4 sacc[4][2];
#pragma unroll
        for (int kt2 = 0; kt2 < 4; ++kt2)
#pragma unroll
            for (int qt2 = 0; qt2 < 2; ++qt2) sacc[kt2][qt2] = (f32x4){0.f, 0.f, 0.f, 0.f};
#pragma unroll
        for (int ks = 0; ks < 4; ++ks) {
            f16x8 kf[4];
#pragma unroll
            for (int kt2 = 0; kt2 < 4; ++kt2) kf[kt2] = *(const f16x8*)&Kl[kt2 * 16 + n][ks * 32 + g * 8];
#pragma unroll
            for (int kt2 = 0; kt2 < 4; ++kt2)
#pragma unroll
                for (int qt2 = 0; qt2 < 2; ++qt2)
                    sacc[kt2][qt2] = __builtin_amdgcn_mfma_f32_16x16x32_f16(kf[kt2], qf[qt2][ks], sacc[kt2][qt2], 0, 0, 0);
        }

        // online softmax per q-column (thread holds 16 keys of column q)
        float al[2];
#pragma unroll
        for (int qt2 = 0; qt2 < 2; ++qt2) {
            float v = sacc[0][qt2][0];
#pragma unroll
            for (int kt2 = 0; kt2 < 4; ++kt2)
#pragma unroll
                for (int r = 0; r < 4; ++r) v = fmaxf(v, sacc[kt2][qt2][r]);
            v = fmaxf(v, __shfl_xor(v, 16));
            v = fmaxf(v, __shfl_xor(v, 32));
            float mn = fmaxf(mreg[qt2], v);
            al[qt2] = exp2f((mreg[qt2] - mn) * L2E);
            mreg[qt2] = mn;
            float rs = 0.f;
#pragma unroll
            for (int kt2 = 0; kt2 < 4; ++kt2) {
                union { f16 h[4]; uint2 u; } pk;
#pragma unroll
                for (int r = 0; r < 4; ++r) {
                    float p = exp2f((sacc[kt2][qt2][r] - mn) * L2E);
                    rs += p;
                    pk.h[r] = (f16)p;
                }
                *(uint2*)&Pw[qt2 * 16 + n][kt2 * 16 + g * 4] = pk.u;
            }
            lsum[qt2] = lsum[qt2] * al[qt2] + rs;   // per-lane partial (lane covers its g keys)
        }
#pragma unroll
        for (int mtc = 0; mtc < 8; ++mtc)
#pragma unroll
            for (int qt2 = 0; qt2 < 2; ++qt2)
#pragma unroll
                for (int r = 0; r < 4; ++r) oacc[mtc][qt2][r] *= al[qt2];

        // phase B: O^T[c][q] += V.P^T  (A=V[c][key], B=P[q][key]; Pw wave-private)
#pragma unroll
        for (int ks = 0; ks < 2; ++ks) {
            f16x8 vf[8], pf[2];
#pragma unroll
            for (int mtc = 0; mtc < 8; ++mtc) vf[mtc] = *(const f16x8*)&Vl[mtc * 16 + n][ks * 32 + g * 8];
#pragma unroll
            for (int qt2 = 0; qt2 < 2; ++qt2) pf[qt2] = *(const f16x8*)&Pw[qt2 * 16 + n][ks * 32 + g * 8];
#pragma unroll
            for (int mtc = 0; mtc < 8; ++mtc)
#pragma unroll
                for (int qt2 = 0; qt2 < 2; ++qt2)
                    oacc[mtc][qt2] = __builtin_amdgcn_mfma_f32_16x16x32_f16(vf[mtc], pf[qt2], oacc[mtc][qt2], 0, 0, 0);
        }
    }

    // final l reduction over g-lanes
    float lreg[2];
#pragma unroll
    for (int qt2 = 0; qt2 < 2; ++qt2) {
        float s = lsum[qt2];
        s += __shfl_xor(s, 16);
        s += __shfl_xor(s, 32);
        lreg[qt2] = s;
    }

    const int pidx = (b * 32 + qt) * 8 + kh;
    if (g == 0) {
        float* MlW = Ml + (size_t)pidx * 256;
#pragma unroll
        for (int qt2 = 0; qt2 < 2; ++qt2) {
            int q = w * 32 + qt2 * 16 + n;
            MlW[q]       = mreg[qt2];
            MlW[128 + q] = lreg[qt2];
        }
    }

    // epilogue: transpose O^T frags through LDS (reuse K/V arena), coalesced store
    __syncthreads();                            // all phase-B reads done
    f16 (*S2)[136] = (f16(*)[136])arena;        // [c][q] 128x136 = 34816 B
#pragma unroll
    for (int mtc = 0; mtc < 8; ++mtc)
#pragma unroll
        for (int qt2 = 0; qt2 < 2; ++qt2)
#pragma unroll
            for (int r = 0; r < 4; ++r)
                S2[mtc * 16 + g * 4 + r][w * 32 + qt2 * 16 + n] = (f16)oacc[mtc][qt2][r];
    __syncthreads();
    f16* OpW = Op + (size_t)pidx * 16384;
#pragma unroll
    for (int i = 0; i < 8; ++i) {
        int vi = tid + i * 256;                 // 0..2047
        int c = vi >> 4, qq = (vi & 15) * 8;
        *(uint4*)&OpW[c * 128 + qq] = *(const uint4*)&S2[c][qq];
    }
}

// ---------------------------------------------------------------- merge (8 partials)
__global__ __launch_bounds__(256) void mrgk(
    const f16* __restrict__ Op, const float* __restrict__ Ml,
    const float* __restrict__ xv, const float* __restrict__ gp, const float* __restrict__ bp,
    float* __restrict__ out)
{
    const int bx = blockIdx.x;                 // (b*32+qt)*4 + cg
    const int cg = bx & 3, bqt = bx >> 2;
    const int b = bqt >> 5, qt = bqt & 31;
    const int tid = threadIdx.x;
    const int q = tid & 127, hf = tid >> 7;

    const float* ml = Ml + (size_t)bqt * 8 * 256;
    float m = -1e30f;
#pragma unroll
    for (int k2 = 0; k2 < 8; ++k2) m = fmaxf(m, ml[k2 * 256 + q]);
    float wt[8], tot = 0.f;
#pragma unroll
    for (int k2 = 0; k2 < 8; ++k2) {
        wt[k2] = exp2f((ml[k2 * 256 + q] - m) * L2E);
        tot += wt[k2] * ml[k2 * 256 + 128 + q];
    }
    float inv = 1.f / tot;
    float gm = gp[0], bb = bp[0];

    const f16* O = Op + (size_t)bqt * 8 * 16384;
#pragma unroll 2
    for (int i = 0; i < 16; ++i) {
        int c = cg * 32 + hf * 16 + i;
        float o = 0.f;
#pragma unroll
        for (int k2 = 0; k2 < 8; ++k2) o += wt[k2] * (float)O[k2 * 16384 + c * 128 + q];
        o *= inv;
        size_t idx = ((size_t)(b * CC + c)) * SS + qt * 128 + q;
        out[idx] = gm * o + bb * xv[idx];
    }
}

// ---------------------------------------------------------------- launcher
extern "C" void kernel_launch(void* const* d_in, const int* in_sizes, int n_in,
                              void* d_out, int out_size, void* d_ws, size_t ws_size,
                              hipStream_t stream) {
    (void)in_sizes; (void)n_in; (void)out_size; (void)ws_size;

    const size_t TEN = (size_t)4 * SS * CC;          // 2,097,152
    f16* Qt = (f16*)d_ws;                            // 4 MB
    f16* Kt = Qt + TEN;                              // 4 MB
    f16* Vt = Kt + TEN;                              // 4 MB (channel-major)
    f16* Op = Vt + TEN;                              // 1024*16384 f16 = 32 MB
    float* Ml = (float*)(Op + (size_t)1024 * 16384); // 1024*256 f32 = 1 MB

    PArg aq = { (const float*)d_in[0], (const float*)d_in[3],  (const float*)d_in[4],
                (const float*)d_in[5], (const float*)d_in[6],  (const float*)d_in[7],
                (const float*)d_in[8],  Qt };
    PArg ak = { (const float*)d_in[1], (const float*)d_in[9],  (const float*)d_in[10],
                (const float*)d_in[11], (const float*)d_in[12], (const float*)d_in[13],
                (const float*)d_in[14], Kt };
    PArg av = { (const float*)d_in[2], (const float*)d_in[15], (const float*)d_in[16],
                (const float*)d_in[17], (const float*)d_in[18], (const float*)d_in[19],
                (const float*)d_in[20], Vt };

    hipLaunchKernelGGL(projk, dim3(256, 3), dim3(256), 0, stream, aq, ak, av);
    hipLaunchKernelGGL(attnk, dim3(1024), dim3(256), 0, stream, Qt, Kt, Vt, Op, Ml);
    hipLaunchKernelGGL(mrgk, dim3(512), dim3(256), 0, stream,
                       Op, Ml, (const float*)d_in[2], (const float*)d_in[21],
                       (const float*)d_in[22], (float*)d_out);
}